// Round 14
// baseline (222.134 us; speedup 1.0000x reference)
//
#include <hip/hip_runtime.h>
#include <hip/hip_bf16.h>
#include <stdint.h>

#define B_   4
#define T_   2048
#define H_   8
#define HD_  64
#define DM_  512
#define N3_  1536

typedef short bf_el;
typedef __attribute__((ext_vector_type(8))) bf_el bfrag;    // 8 bf16 = 4 VGPRs
typedef __attribute__((ext_vector_type(4))) bf_el bfrag4;   // 4 bf16 = 2 VGPRs
typedef __attribute__((ext_vector_type(4))) float ffrag;

#define SCALE_L2E  0.18033688011112043f   /* 0.125 * log2(e) */
#define MASK_L2E   14426.950408889634f    /* 1e4  * log2(e) */

static __device__ __forceinline__ unsigned short f2bf(float f) {      // RNE
    union { float f; unsigned int i; } v; v.f = f;
    unsigned int r = v.i + 0x7fff + ((v.i >> 16) & 1);
    return (unsigned short)(r >> 16);
}
static __device__ __forceinline__ unsigned short f2bf_fast(float f) { // round-half-up
    union { float f; unsigned int i; } v; v.f = f;
    return (unsigned short)((v.i + 0x8000u) >> 16);
}

// ---------------------------------------------------------------------------
// Kernel 0 (prep): W [512,1536] fp32 -> Wt bf16 [1536,512]. 192 blocks only.
// (X conversion moved into the GEMM staging; Xb intermediate eliminated.)
// ---------------------------------------------------------------------------
__global__ __launch_bounds__(256) void k_prep(const float* __restrict__ W,
                                              unsigned short* __restrict__ Wt) {
    __shared__ __align__(16) unsigned short Ls[64 * 72];
    const int t  = blockIdx.x;                // 0..191 = 24 x 8
    const int n0 = (t % 24) * 64;
    const int k0 = (t / 24) * 64;
    const int tid = threadIdx.x;
#pragma unroll
    for (int i = 0; i < 4; ++i) {
        int chunk = tid + i * 256;
        int k = chunk >> 4;
        int c = chunk & 15;
        float4 f = *(const float4*)(W + (size_t)(k0 + k) * N3_ + n0 + c * 4);
        unsigned short* p = Ls + k * 72 + c * 4;
        p[0] = f2bf(f.x); p[1] = f2bf(f.y); p[2] = f2bf(f.z); p[3] = f2bf(f.w);
    }
    __syncthreads();
    const int n = tid >> 2;
    const int g = tid & 3;
    __align__(16) unsigned short tmp[16];
#pragma unroll
    for (int i = 0; i < 16; ++i) tmp[i] = Ls[(g * 16 + i) * 72 + n];
    uint4* dst = (uint4*)(Wt + (size_t)(n0 + n) * DM_ + k0 + g * 16);
    dst[0] = *(const uint4*)(tmp);
    dst[1] = *(const uint4*)(tmp + 8);
}

// ---------------------------------------------------------------------------
// Kernel 1 (fused GEMM + interleaved mask scan). 1536 blocks:
//  bid%3==2 -> SCAN: contiguous 128KB of mask; atomicOr(anymask) on mismatch.
//  else     -> GEMM: X fp32 read directly (fp32->bf16 in A staging),
//              64x192 tile (one head), kt+1 register prefetch.
// ---------------------------------------------------------------------------
__global__ __launch_bounds__(256, 4) void k_gemm_qkv(const float* __restrict__ X,
                                                     const unsigned short* __restrict__ Wt,
                                                     const float* __restrict__ bias,
                                                     const float* __restrict__ mask,
                                                     int* __restrict__ anymask,
                                                     unsigned short* __restrict__ Qb,
                                                     unsigned short* __restrict__ Kb,
                                                     unsigned short* __restrict__ Vtb) {
    __shared__ __align__(16) unsigned short SH[12800];
    const int tid = threadIdx.x;
    const int g3  = blockIdx.x / 3;
    const int r3  = blockIdx.x - g3 * 3;

    if (r3 == 2) {
        // ---------------- mask-scan role (512 blocks) ----------------
        const int R0 = g3 * 16;               // 16 consecutive mask rows
        unsigned int acc = 0u;
        const float* base = mask + (size_t)R0 * T_ + tid * 8;
#pragma unroll
        for (int rr = 0; rr < 16; ++rr) {
            const uint4 u0 = *(const uint4*)(base + (size_t)rr * T_);
            const uint4 u1 = *(const uint4*)(base + (size_t)rr * T_ + 4);
            acc |= (u0.x ^ 0x3F800000u) | (u0.y ^ 0x3F800000u) |
                   (u0.z ^ 0x3F800000u) | (u0.w ^ 0x3F800000u) |
                   (u1.x ^ 0x3F800000u) | (u1.y ^ 0x3F800000u) |
                   (u1.z ^ 0x3F800000u) | (u1.w ^ 0x3F800000u);
        }
        unsigned long long bal = __ballot(acc != 0u);
        if ((tid & 63) == 0 && bal != 0ULL) atomicOr(anymask, 1);
        return;
    }

    // ---------------- GEMM role (1024 blocks) ----------------
    unsigned short* As = SH;            // row stride 40 shorts
    unsigned short* Bs = SH + 2560;
    unsigned short* Cs = SH;            // row stride 200 shorts

    const int gemm_id = g3 * 2 + r3;    // 0..1023
    const int wave = tid >> 6;
    const int lane = tid & 63;
    const int quad = lane >> 4;
    const int l16  = lane & 15;
    const int wm = wave >> 1, wn = wave & 1;
    const int h  = gemm_id >> 7;
    const int m0 = (gemm_id & 127) * 64;
    const int n0 = h * 192;

    float bvv[6];
#pragma unroll
    for (int ni = 0; ni < 6; ++ni) bvv[ni] = bias[n0 + wn * 96 + ni * 16 + l16];

    ffrag acc[2][6];
#pragma unroll
    for (int i = 0; i < 2; ++i)
#pragma unroll
        for (int j = 0; j < 6; ++j) acc[i][j] = (ffrag){0.f, 0.f, 0.f, 0.f};

    const int ar = tid >> 2, ac = tid & 3;          // A: 1 chunk (8 elems) / thread
    const int br0 = tid >> 2, br1 = (tid + 256) >> 2, br2 = (tid + 512) >> 2;
    const int bc  = tid & 3;
    float4 pa0, pa1;
    uint4  pb0, pb1, pb2;

    {
        const float* xp = X + (size_t)(m0 + ar) * DM_ + ac * 8;
        pa0 = *(const float4*)xp; pa1 = *(const float4*)(xp + 4);
        pb0 = *(const uint4*)(Wt + (size_t)(n0 + br0) * DM_ + bc * 8);
        pb1 = *(const uint4*)(Wt + (size_t)(n0 + br1) * DM_ + bc * 8);
        pb2 = *(const uint4*)(Wt + (size_t)(n0 + br2) * DM_ + bc * 8);
    }

    for (int kt = 0; kt < 16; ++kt) {
        __syncthreads();
        {
            __align__(16) unsigned short t8[8];
            t8[0] = f2bf_fast(pa0.x); t8[1] = f2bf_fast(pa0.y);
            t8[2] = f2bf_fast(pa0.z); t8[3] = f2bf_fast(pa0.w);
            t8[4] = f2bf_fast(pa1.x); t8[5] = f2bf_fast(pa1.y);
            t8[6] = f2bf_fast(pa1.z); t8[7] = f2bf_fast(pa1.w);
            *(uint4*)(As + ar * 40 + ac * 8) = *(const uint4*)t8;
        }
        *(uint4*)(Bs + br0 * 40 + bc * 8) = pb0;
        *(uint4*)(Bs + br1 * 40 + bc * 8) = pb1;
        *(uint4*)(Bs + br2 * 40 + bc * 8) = pb2;
        __syncthreads();
        if (kt < 15) {
            const int ko = (kt + 1) * 32;
            const float* xp = X + (size_t)(m0 + ar) * DM_ + ko + ac * 8;
            pa0 = *(const float4*)xp; pa1 = *(const float4*)(xp + 4);
            pb0 = *(const uint4*)(Wt + (size_t)(n0 + br0) * DM_ + ko + bc * 8);
            pb1 = *(const uint4*)(Wt + (size_t)(n0 + br1) * DM_ + ko + bc * 8);
            pb2 = *(const uint4*)(Wt + (size_t)(n0 + br2) * DM_ + ko + bc * 8);
        }
        bfrag af[2], bfr[6];
#pragma unroll
        for (int mi = 0; mi < 2; ++mi)
            af[mi] = *(const bfrag*)(As + (wm * 32 + mi * 16 + l16) * 40 + quad * 8);
#pragma unroll
        for (int ni = 0; ni < 6; ++ni)
            bfr[ni] = *(const bfrag*)(Bs + (wn * 96 + ni * 16 + l16) * 40 + quad * 8);
#pragma unroll
        for (int mi = 0; mi < 2; ++mi)
#pragma unroll
            for (int ni = 0; ni < 6; ++ni)
                acc[mi][ni] = __builtin_amdgcn_mfma_f32_16x16x32_bf16(af[mi], bfr[ni], acc[mi][ni], 0, 0, 0);
    }

    const int b  = m0 >> 11;
    const int tb = m0 & 2047;
    const size_t bh = (size_t)(b * 8 + h);
    float cscale[6];
#pragma unroll
    for (int ni = 0; ni < 6; ++ni) {
        int c = wn * 96 + ni * 16 + l16;
        cscale[ni] = (c % 3 == 0) ? SCALE_L2E : 1.0f;
    }
    __syncthreads();
#pragma unroll
    for (int mi = 0; mi < 2; ++mi)
#pragma unroll
        for (int ni = 0; ni < 6; ++ni)
#pragma unroll
            for (int reg = 0; reg < 4; ++reg) {
                int r = wm * 32 + mi * 16 + quad * 4 + reg;
                int c = wn * 96 + ni * 16 + l16;
                Cs[r * 200 + c] = f2bf_fast((acc[mi][ni][reg] + bvv[ni]) * cscale[ni]);
            }
    __syncthreads();
#pragma unroll
    for (int i = 0; i < 2; ++i) {
        int idx = tid + i * 256;
        int tl = idx >> 3, hc = (idx & 7) * 8;
        __align__(16) unsigned short tq[8], tk[8];
#pragma unroll
        for (int j = 0; j < 8; ++j) {
            tq[j] = Cs[tl * 200 + (hc + j) * 3 + 0];
            tk[j] = Cs[tl * 200 + (hc + j) * 3 + 1];
        }
        *(uint4*)(Qb + (bh * T_ + tb + tl) * HD_ + hc) = *(const uint4*)tq;
        *(uint4*)(Kb + (bh * T_ + tb + tl) * HD_ + hc) = *(const uint4*)tk;
    }
#pragma unroll
    for (int i = 0; i < 2; ++i) {
        int idx = tid + i * 256;
        int hd = idx >> 3, t8 = (idx & 7) * 8;
        __align__(16) unsigned short tv[8];
#pragma unroll
        for (int j = 0; j < 8; ++j)
            tv[j] = Cs[(t8 + j) * 200 + hd * 3 + 2];
        *(uint4*)(Vtb + (bh * HD_ + hd) * T_ + tb + t8) = *(const uint4*)tv;
    }
}

// ---------------------------------------------------------------------------
// Kernel 2: flash attention, S^T formulation + double-buffered K/V pipeline.
// lsum now accumulated in the MFMA pipe: lacc = mfma(ones, pf, lacc) —
// A=ones => D[m][q] += sum_k P[k][q]; all regs/quads identical => no VALU
// adds, no epilogue shuffles. Global any-mask flag (all-ones mask: zero work).
// 64-q tile, grid 1024 (4 blocks/CU), bid = qt*32+bh (XCD=bh%8).
// ---------------------------------------------------------------------------
__global__ __launch_bounds__(256) void k_attn(const unsigned short* __restrict__ Q,
                                              const unsigned short* __restrict__ K,
                                              const unsigned short* __restrict__ Vt,
                                              const float* __restrict__ mask,
                                              const int* __restrict__ anymask,
                                              float* __restrict__ out) {
    __shared__ __align__(16) unsigned short Ks[2][64 * 72];
    __shared__ __align__(16) unsigned short Vs[2][64 * 72];   // [dim][kv]

    const int tid = threadIdx.x;
    const int wave = tid >> 6, lane = tid & 63;
    const int quad = lane >> 4, l16 = lane & 15;
    const int bh = blockIdx.x & 31, b = bh >> 3, h = bh & 7;
    const int qt = blockIdx.x >> 5;      // 0..31
    const int q0 = qt * 64;
    const int q = q0 + wave * 16 + l16;  // this lane's q row

    const int gmask = anymask[0];

    bfrag qf[2];
    {
        size_t qrow = ((size_t)bh * T_ + q) * HD_;
        qf[0] = *(const bfrag*)(Q + qrow + quad * 8);
        qf[1] = *(const bfrag*)(Q + qrow + 32 + quad * 8);
    }
    const bfrag4 ones = (bfrag4){(bf_el)0x3F80, (bf_el)0x3F80, (bf_el)0x3F80, (bf_el)0x3F80};
    ffrag lacc = (ffrag){0.f, 0.f, 0.f, 0.f};   // row-sum accumulator (MFMA pipe)
    ffrag of[4];                                // O^T d-tiles
#pragma unroll
    for (int dt = 0; dt < 4; ++dt) of[dt] = (ffrag){0.f, 0.f, 0.f, 0.f};

    const int sr0 = tid >> 3, sr1 = (tid + 256) >> 3, sc = tid & 7;
    const unsigned short* Kbase = K  + (size_t)bh * T_ * HD_;
    const unsigned short* Vbase = Vt + (size_t)bh * HD_ * T_;
    const float* mq = mask + ((size_t)b * T_ + q) * T_;

    uint4 kreg[2], vreg[2];
    kreg[0] = *(const uint4*)(Kbase + (size_t)sr0 * HD_ + sc * 8);
    kreg[1] = *(const uint4*)(Kbase + (size_t)sr1 * HD_ + sc * 8);
    vreg[0] = *(const uint4*)(Vbase + (size_t)sr0 * T_ + sc * 8);
    vreg[1] = *(const uint4*)(Vbase + (size_t)sr1 * T_ + sc * 8);
    *(uint4*)(&Ks[0][sr0 * 72 + sc * 8]) = kreg[0];
    *(uint4*)(&Ks[0][sr1 * 72 + sc * 8]) = kreg[1];
    *(uint4*)(&Vs[0][sr0 * 72 + sc * 8]) = vreg[0];
    *(uint4*)(&Vs[0][sr1 * 72 + sc * 8]) = vreg[1];
    __syncthreads();

    for (int kt = 0; kt < 32; ++kt) {
        const int cur = kt & 1;
        if (kt < 31) {                    // issue kt+1 loads; drain after compute
            const int kn = (kt + 1) * 64;
            kreg[0] = *(const uint4*)(Kbase + (size_t)(kn + sr0) * HD_ + sc * 8);
            kreg[1] = *(const uint4*)(Kbase + (size_t)(kn + sr1) * HD_ + sc * 8);
            vreg[0] = *(const uint4*)(Vbase + (size_t)sr0 * T_ + kn + sc * 8);
            vreg[1] = *(const uint4*)(Vbase + (size_t)sr1 * T_ + kn + sc * 8);
        }
#pragma unroll
        for (int ns = 0; ns < 4; ++ns) {
            // S^T: D = K(A) * Q^T(B); lane: q=l16, kv=kt*64+ns*16+quad*4+reg
            ffrag a = (ffrag){0.f, 0.f, 0.f, 0.f};
#pragma unroll
            for (int ks = 0; ks < 2; ++ks) {
                bfrag kf = *(const bfrag*)(&Ks[cur][(ns * 16 + l16) * 72 + (ks * 4 + quad) * 8]);
                a = __builtin_amdgcn_mfma_f32_16x16x32_bf16(kf, qf[ks], a, 0, 0, 0);
            }
            // p = exp2(s [+ maskbias]); pack into 16x16x16 B-fragment
            bfrag4 pf;
            if (gmask) {
                const float* mp = mq + kt * 64 + ns * 16 + quad * 4;
#pragma unroll
                for (int reg = 0; reg < 4; ++reg) {
                    float p = __builtin_amdgcn_exp2f(
                        fmaf(mp[reg], MASK_L2E, a[reg] - MASK_L2E));
                    pf[reg] = (bf_el)f2bf_fast(p);
                }
            } else {
#pragma unroll
                for (int reg = 0; reg < 4; ++reg) {
                    float p = __builtin_amdgcn_exp2f(a[reg]);
                    pf[reg] = (bf_el)f2bf_fast(p);
                }
            }
            // row-sum in the MFMA pipe (A = ones)
            lacc = __builtin_amdgcn_mfma_f32_16x16x16bf16_1k(ones, pf, lacc, 0, 0, 0);
            // O^T += V^T(A) * P^T(B)
#pragma unroll
            for (int dt = 0; dt < 4; ++dt) {
                bfrag4 vf = *(const bfrag4*)(&Vs[cur][(dt * 16 + l16) * 72 + ns * 16 + quad * 4]);
                of[dt] = __builtin_amdgcn_mfma_f32_16x16x16bf16_1k(vf, pf, of[dt], 0, 0, 0);
            }
        }
        if (kt < 31) {                    // write staged kt+1, one barrier
            const int nxt = cur ^ 1;
            *(uint4*)(&Ks[nxt][sr0 * 72 + sc * 8]) = kreg[0];
            *(uint4*)(&Ks[nxt][sr1 * 72 + sc * 8]) = kreg[1];
            *(uint4*)(&Vs[nxt][sr0 * 72 + sc * 8]) = vreg[0];
            *(uint4*)(&Vs[nxt][sr1 * 72 + sc * 8]) = vreg[1];
            __syncthreads();
        }
    }
    // epilogue: lacc[0] already holds the full row-sum (P rounded to bf16,
    // matching the P used in PV). Normalize, float4 store.
    const float inv = 1.0f / lacc[0];
    float* orow = out + ((size_t)b * T_ + q) * DM_ + h * 64;
#pragma unroll
    for (int dt = 0; dt < 4; ++dt) {
        float4 v;
        v.x = of[dt][0] * inv; v.y = of[dt][1] * inv;
        v.z = of[dt][2] * inv; v.w = of[dt][3] * inv;
        *(float4*)(orow + dt * 16 + quad * 4) = v;
    }
}

// ---------------------------------------------------------------------------
extern "C" void kernel_launch(void* const* d_in, const int* in_sizes, int n_in,
                              void* d_out, int out_size, void* d_ws, size_t ws_size,
                              hipStream_t stream) {
    const float* X    = (const float*)d_in[0];   // [4,2048,512] fp32
    const float* mask = (const float*)d_in[1];   // [4,1,2048,2048] fp32
    const float* W    = (const float*)d_in[2];   // [512,1536] fp32
    const float* bias = (const float*)d_in[3];   // [1536] fp32
    float* outp = (float*)d_out;                 // [4,2048,512] fp32

    char* ws = (char*)d_ws;
    unsigned short* Wt  = (unsigned short*)(ws);              // 1.5 MB
    unsigned short* Qb  = (unsigned short*)(ws + 1572864);    // 8 MB
    unsigned short* Kb  = (unsigned short*)(ws + 9961472);    // 8 MB
    unsigned short* Vtb = (unsigned short*)(ws + 18350080);   // 8 MB
    int*            flg = (int*)(ws + 26738688);              // 4 B

    hipMemsetAsync(flg, 0, 4, stream);
    k_prep     <<<dim3(192),  256, 0, stream>>>(W, Wt);
    k_gemm_qkv <<<dim3(1536), 256, 0, stream>>>(X, Wt, bias, mask, flg, Qb, Kb, Vtb);
    k_attn     <<<dim3(1024), 256, 0, stream>>>(Qb, Kb, Vtb, mask, flg, outp);
}